// Round 6
// baseline (339.993 us; speedup 1.0000x reference)
//
#include <hip/hip_runtime.h>
#include <stdint.h>

#define T_LEN 512
#define NTOK  1536   // (1+NGRAM)*T
#define EMB   1024
#define BS    4

typedef __bf16 bf16x8 __attribute__((ext_vector_type(8)));
typedef float  f32x4  __attribute__((ext_vector_type(4)));

__device__ __forceinline__ float bflo(unsigned short u){
  union { unsigned int i; float f; } a; a.i = ((unsigned int)u) << 16; return a.f;
}
__device__ __forceinline__ unsigned short f2bf(float f){
  union { float f; unsigned int i; } v; v.f = f;
  unsigned int x = v.i;
  return (unsigned short)((x + 0x7fffu + ((x >> 16) & 1u)) >> 16); // RNE
}

__device__ __forceinline__ void gld_lds16(const unsigned short* gptr, unsigned short* lptr){
  __builtin_amdgcn_global_load_lds(
      (const __attribute__((address_space(1))) unsigned int*)gptr,
      (__attribute__((address_space(3))) unsigned int*)lptr, 16, 0, 0);
}

// ---------------------------------------------------------------------------
// fp32 -> bf16 cast pre-pass (hidden, wqkv++relw, outw). 8 elems/thread.
// ---------------------------------------------------------------------------
__global__ __launch_bounds__(256)
void cast_k(const float* __restrict__ h, const float* __restrict__ wq,
            const float* __restrict__ rw, const float* __restrict__ ow,
            unsigned short* __restrict__ Hb, unsigned short* __restrict__ Wc,
            unsigned short* __restrict__ Ob)
{
  const size_t e = ((size_t)blockIdx.x * 256 + threadIdx.x) * 8;
  const float* src; unsigned short* dst;
  if (e < 6291456)            { src = h  + e;                 dst = Hb + e; }
  else if (e < 9437184)       { size_t o = e - 6291456;       src = wq + o; dst = Wc + o; }
  else if (e < 9961472)       { size_t o = e - 9437184;       src = rw + o; dst = Wc + 3145728 + o; }
  else                        { size_t o = e - 9961472;       src = ow + o; dst = Ob + o; }
  float4 f0 = *(const float4*)src, f1 = *(const float4*)(src + 4);
  unsigned short r[8];
  r[0]=f2bf(f0.x); r[1]=f2bf(f0.y); r[2]=f2bf(f0.z); r[3]=f2bf(f0.w);
  r[4]=f2bf(f1.x); r[5]=f2bf(f1.y); r[6]=f2bf(f1.z); r[7]=f2bf(f1.w);
  *(uint4*)dst = *(const uint4*)r;
}

// ---------------------------------------------------------------------------
// bf16 MFMA GEMM computing C^T: A-operand frags = WEIGHT rows, B-operand
// frags = HIDDEN (token) rows, so D's m-dim = out-col, n-dim = token. The 4
// C/D regs per lane then span 4 CONSECUTIVE out-cols (= consecutive d within
// one head) -> vectorized epilogue stores (uint2 bf16x4 / float4) instead of
// 64x 2-byte scatter. Single-panel BK=32 (R4 structure; dual-panel was
// neutral-negative in R5).
// MODE 0: 128-token tiles, W=Wc(3584 rows: 3072 qkv + 512 rel). Epilogue:
//   Q (x0.125) -> bf16 [bh][tok][64]; K -> bf16 [bh][tok][64];
//   V -> bf16 NATURAL [bh][tok][64] (vtr kernel transposes later);
//   rel-vals -> fp32 [bh][tok][32] (scatter, 4/28 of x-blocks only).
// MODE 1: 64-token tiles (768 blocks vs 384: the 1.5-block/CU grid was
//   latency-exposed), W=Ob(outw), +outb -> fp32 d_out via float4.
// ---------------------------------------------------------------------------
template<int MODE>
__global__ __launch_bounds__(256)
void mgemm(const unsigned short* __restrict__ A,
           const unsigned short* __restrict__ W,
           const float* __restrict__ B0,
           const float* __restrict__ B1,
           unsigned short* __restrict__ Qo, unsigned short* __restrict__ Ko,
           unsigned short* __restrict__ Vo, float* __restrict__ VALS,
           float* __restrict__ OUT)
{
  constexpr int TM = (MODE == 0) ? 128 : 64;   // token rows per block
  constexpr int NI = (MODE == 0) ? 4 : 2;      // weight-col frags per wave
  __shared__ unsigned short As[TM*32];
  __shared__ unsigned short Bs[128*32];
  const int K = 1024;
  const int m0 = blockIdx.y * TM, n0 = blockIdx.x * 128;
  const int tid = threadIdx.x;
  const int wid = tid >> 6, lane = tid & 63;
  const int l15 = lane & 15, q8 = (lane >> 4) * 8;
  const int srow = lane >> 2, schunk = (lane & 3) * 8;
  const int wcol = (MODE == 0) ? (wid >> 1) * 64 : wid * 32;
  const int wtok = (MODE == 0) ? (wid & 1) * 64 : 0;

  f32x4 acc[NI][4];
  #pragma unroll
  for (int i=0;i<NI;i++)
    #pragma unroll
    for (int j=0;j<4;j++)
      #pragma unroll
      for (int r=0;r<4;r++) acc[i][j][r] = 0.f;

  for (int k0 = 0; k0 < K; k0 += 32) {
    if (MODE == 0) {
      #pragma unroll
      for (int p = 0; p < 2; ++p) {
        const int r0 = p*64 + wid*16;
        gld_lds16(A + (size_t)(m0 + r0 + srow)*K + k0 + schunk, &As[r0*32]);
      }
    } else {
      const int r0 = wid*16;
      gld_lds16(A + (size_t)(m0 + r0 + srow)*K + k0 + schunk, &As[r0*32]);
    }
    #pragma unroll
    for (int p = 0; p < 2; ++p) {
      const int r0 = p*64 + wid*16;
      gld_lds16(W + (size_t)(n0 + r0 + srow)*K + k0 + schunk, &Bs[r0*32]);
    }
    __syncthreads();
    bf16x8 wf[NI], hf[4];
    #pragma unroll
    for (int i=0;i<NI;i++) wf[i] = *(const bf16x8*)&Bs[(wcol + i*16 + l15)*32 + q8];
    #pragma unroll
    for (int j=0;j<4;j++)  hf[j] = *(const bf16x8*)&As[(wtok + j*16 + l15)*32 + q8];
    #pragma unroll
    for (int i=0;i<NI;i++)
      #pragma unroll
      for (int j=0;j<4;j++)
        acc[i][j] = __builtin_amdgcn_mfma_f32_16x16x32_bf16(wf[i], hf[j], acc[i][j], 0, 0, 0);
    __syncthreads();
  }

  // D layout: n(token) = l15 (+16j+wtok+m0); m(out-col) = rbase+r (+16i+wcol+n0)
  const int rbase = (lane >> 4) * 4;
  #pragma unroll
  for (int i=0;i<NI;i++){
    const int c0 = n0 + wcol + i*16 + rbase;     // 4 consecutive cols c0..c0+3
    float4 b4;
    if (MODE==0) b4 = (c0 < 3072) ? *(const float4*)&B0[c0]
                                  : *(const float4*)&B1[c0-3072];
    else         b4 = *(const float4*)&B0[c0];
    #pragma unroll
    for (int j=0;j<4;j++){
      const int tokrow = m0 + wtok + j*16 + l15; // = tok*B + b
      float v[4];
      v[0]=acc[i][j][0]+b4.x; v[1]=acc[i][j][1]+b4.y;
      v[2]=acc[i][j][2]+b4.z; v[3]=acc[i][j][3]+b4.w;
      if (MODE==1){
        float4 st; st.x=v[0]; st.y=v[1]; st.z=v[2]; st.w=v[3];
        *(float4*)&OUT[(size_t)tokrow*EMB + c0] = st;
      } else {
        const int tok = tokrow >> 2, bb = tokrow & 3;
        if (c0 < 3072){
          const int which = c0 >> 10, e = c0 & 1023;
          const int h = e >> 6, d0 = e & 63;      // d0..d0+3 same head
          const float sc = (which==0) ? 0.125f : 1.0f;
          unsigned short pk[4];
          #pragma unroll
          for (int r=0;r<4;r++) pk[r] = f2bf(v[r]*sc);
          unsigned short* base = (which==0) ? Qo : (which==1) ? Ko : Vo;
          *(uint2*)&base[((size_t)(bb*16+h)*NTOK + tok)*64 + d0] = *(const uint2*)pk;
        } else {
          const int nb = (c0 - 3072) >> 4;        // h = rbase+r, nb uniform
          #pragma unroll
          for (int r=0;r<4;r++)
            VALS[((size_t)(bb*16 + rbase + r)*NTOK + tok)*32 + nb] = v[r];
        }
      }
    }
  }
}

// ---------------------------------------------------------------------------
// V transpose: Vn [bh][tok][64] -> VT [bh][d][tok]. 64x64 tiles via LDS
// (row pad 72 shorts = 144B: 16B-aligned writes, 2-way bank alias on reads).
// ---------------------------------------------------------------------------
__global__ __launch_bounds__(256)
void vtr(const unsigned short* __restrict__ Vn, unsigned short* __restrict__ VT)
{
  __shared__ unsigned short t[64*72];
  const int bh = blockIdx.y, t0 = blockIdx.x * 64;
  const int tid = threadIdx.x;
  const int row = tid & 63, seg = tid >> 6;
  const unsigned short* src = Vn + ((size_t)bh*NTOK + t0 + row)*64 + seg*16;
  *(uint4*)&t[row*72 + seg*16]     = *(const uint4*)src;
  *(uint4*)&t[row*72 + seg*16 + 8] = *(const uint4*)(src + 8);
  __syncthreads();
  unsigned short v[16];
  #pragma unroll
  for (int k=0;k<16;k++) v[k] = t[(seg*16+k)*72 + row];
  unsigned short* dst = VT + ((size_t)bh*64 + row)*NTOK + t0 + seg*16;
  *(uint4*)dst       = *(const uint4*)&v[0];
  *(uint4*)(dst + 8) = *(const uint4*)&v[8];
}

// ---------------------------------------------------------------------------
// MFMA flash attention (unchanged from R4/R5). Block = (stream,bh,qi): 64
// q-rows, 4 waves x 16 rows; K/V frags software-pipelined one tile ahead.
// S^T = mfma(A=K,B=Q); p = (u<=t) ? exp(s + VALS[q][bucket(t-u+ofs)]) : 0;
// P -> per-wave LDS [16 q][64 key] bf16 (pad 72); O += mfma(A=P, B=V^T).
// Ngram streams add exactly one extra key at token qtok (bucket fs[0]).
// ---------------------------------------------------------------------------
__global__ __launch_bounds__(256)
void fattn(const unsigned short* __restrict__ Q,
           const unsigned short* __restrict__ K,
           const unsigned short* __restrict__ VT,
           const float* __restrict__ VALS,
           const int* __restrict__ IBM,
           const int* __restrict__ IBN,
           unsigned short* __restrict__ OUT)
{
  __shared__ unsigned short Pl[4][16*72];
  __shared__ float vls[64*33];
  __shared__ int fs[513];

  const int blk = blockIdx.x;
  const int qi = 7 - (blk & 7), sbh = blk >> 3;
  const int stream = sbh >> 6, bh = sbh & 63;
  const int tid = threadIdx.x, wid = tid >> 6, lane = tid & 63;
  const int l15 = lane & 15, q4 = lane >> 4;
  const int tokbase = stream*T_LEN + qi*64;
  const int relofs = (stream > 0) ? 1 : 0;

  fs[tid]       = IBM[(size_t)tid * T_LEN];
  fs[tid + 256] = IBM[(size_t)(tid + 256) * T_LEN];
  if (tid == 0) fs[512] = IBN[(size_t)511 * (2*T_LEN)];
  {
    const int row = tid >> 2, c8 = (tid & 3) * 8;
    const float* vsrc = VALS + ((size_t)bh*NTOK + tokbase + row)*32 + c8;
    *(float4*)&vls[row*33 + c8]     = *(const float4*)vsrc;
    *(float4*)&vls[row*33 + c8 + 4] = *(const float4*)(vsrc + 4);
  }

  const int t = qi*64 + wid*16 + l15;
  const int qtok_l = tokbase + wid*16 + l15;

  bf16x8 bq[2];
  {
    const unsigned short* qp = Q + ((size_t)bh*NTOK + qtok_l)*64 + q4*8;
    bq[0] = *(const bf16x8*)qp;
    bq[1] = *(const bf16x8*)(qp + 32);
  }

  const unsigned short* Kbh = K  + (size_t)bh*NTOK*64;
  const unsigned short* Vbh = VT + (size_t)bh*64*NTOK;

  f32x4 o[4];
  #pragma unroll
  for (int jd=0;jd<4;jd++)
    #pragma unroll
    for (int r=0;r<4;r++) o[jd][r] = 0.f;
  float lreg = 0.f;
  const f32x4 zero = {0.f,0.f,0.f,0.f};
  unsigned short* Pw = &Pl[wid][0];

  bf16x8 ka0[4], ka1[4], vb0[4], vb1[4];
  #pragma unroll
  for (int i=0;i<4;i++){
    const unsigned short* kp = Kbh + (size_t)(16*i + l15)*64 + q4*8;
    ka0[i] = *(const bf16x8*)kp;  ka1[i] = *(const bf16x8*)(kp + 32);
    const unsigned short* vp = Vbh + (size_t)(16*i + l15)*NTOK + q4*8;
    vb0[i] = *(const bf16x8*)vp;  vb1[i] = *(const bf16x8*)(vp + 32);
  }

  __syncthreads();

  const int ntiles = qi + 1;
  for (int tile = 0; tile < ntiles; ++tile) {
    const int u0 = tile * 64;
    bf16x8 nk0[4], nk1[4], nv0[4], nv1[4];
    if (tile + 1 < ntiles) {
      const int nu = u0 + 64;
      #pragma unroll
      for (int i=0;i<4;i++){
        const unsigned short* kp = Kbh + (size_t)(nu + 16*i + l15)*64 + q4*8;
        nk0[i] = *(const bf16x8*)kp;  nk1[i] = *(const bf16x8*)(kp + 32);
        const unsigned short* vp = Vbh + (size_t)(16*i + l15)*NTOK + nu + q4*8;
        nv0[i] = *(const bf16x8*)vp;  nv1[i] = *(const bf16x8*)(vp + 32);
      }
    }
    f32x4 st[4];
    #pragma unroll
    for (int i=0;i<4;i++){
      st[i] = __builtin_amdgcn_mfma_f32_16x16x32_bf16(ka0[i], bq[0], zero, 0, 0, 0);
      st[i] = __builtin_amdgcn_mfma_f32_16x16x32_bf16(ka1[i], bq[1], st[i], 0, 0, 0);
    }
    float lp = 0.f;
    #pragma unroll
    for (int i=0;i<4;i++){
      unsigned short pr4[4];
      #pragma unroll
      for (int r=0;r<4;r++){
        const int u = u0 + 16*i + q4*4 + r;
        const bool ok = (u <= t);
        const int nd = ok ? (t - u + relofs) : 0;
        const float rel = vls[(wid*16 + l15)*33 + fs[nd]];
        float p = ok ? __expf(st[i][r] + rel) : 0.f;
        const unsigned short pb = f2bf(p);
        pr4[r] = pb;
        lp += bflo(pb);
      }
      uint2 pk;
      pk.x = (unsigned int)pr4[0] | ((unsigned int)pr4[1] << 16);
      pk.y = (unsigned int)pr4[2] | ((unsigned int)pr4[3] << 16);
      *(uint2*)&Pw[l15*72 + 16*i + q4*4] = pk;
    }
    lp += __shfl_xor(lp, 16);
    lp += __shfl_xor(lp, 32);
    lreg += lp;
    bf16x8 ap0 = *(const bf16x8*)&Pw[l15*72 + q4*8];
    bf16x8 ap1 = *(const bf16x8*)&Pw[l15*72 + 32 + q4*8];
    #pragma unroll
    for (int jd=0;jd<4;jd++){
      o[jd] = __builtin_amdgcn_mfma_f32_16x16x32_bf16(ap0, vb0[jd], o[jd], 0, 0, 0);
      o[jd] = __builtin_amdgcn_mfma_f32_16x16x32_bf16(ap1, vb1[jd], o[jd], 0, 0, 0);
    }
    if (tile + 1 < ntiles) {
      #pragma unroll
      for (int i=0;i<4;i++){
        ka0[i]=nk0[i]; ka1[i]=nk1[i]; vb0[i]=nv0[i]; vb1[i]=nv1[i];
      }
    }
  }

  __shared__ float pex[4][16];
  __shared__ float lar[4][16];

  if (stream > 0) {
    const unsigned short* qp2 = Q + ((size_t)bh*NTOK + qtok_l)*64 + q4*16;
    const unsigned short* kp2 = Kbh + (size_t)qtok_l*64 + q4*16;
    float s = 0.f;
    #pragma unroll
    for (int c=0;c<2;c++){
      bf16x8 qv = *(const bf16x8*)(qp2 + c*8);
      bf16x8 kv = *(const bf16x8*)(kp2 + c*8);
      #pragma unroll
      for (int e=0;e<8;e++) s += (float)qv[e] * (float)kv[e];
    }
    s += __shfl_xor(s, 16);
    s += __shfl_xor(s, 32);
    const float p = __expf(s + vls[(wid*16 + l15)*33 + fs[0]]);
    lreg += p;
    pex[wid][l15] = p;
    #pragma unroll
    for (int r=0;r<4;r++){
      const int qloc = q4*4 + r;
      const float pq = pex[wid][qloc];
      const int qtk = tokbase + wid*16 + qloc;
      #pragma unroll
      for (int jd=0;jd<4;jd++){
        const float vv = bflo(Vbh[(size_t)(16*jd + l15)*NTOK + qtk]);
        o[jd][r] += pq * vv;
      }
    }
  }

  lar[wid][l15] = lreg;

  const int b = bh >> 4, h = bh & 15;
  #pragma unroll
  for (int r=0;r<4;r++){
    const int qloc = q4*4 + r;
    const float inv = 1.0f / lar[wid][qloc];
    const int qtk = tokbase + wid*16 + qloc;
    unsigned short* orow = OUT + ((size_t)qtk*BS + b)*EMB + h*64 + l15;
    #pragma unroll
    for (int jd=0;jd<4;jd++)
      orow[16*jd] = f2bf(o[jd][r] * inv);
  }
}

// ---------------------------------------------------------------------------
extern "C" void kernel_launch(void* const* d_in, const int* in_sizes, int n_in,
                              void* d_out, int out_size, void* d_ws, size_t ws_size,
                              hipStream_t stream) {
  (void)in_sizes; (void)n_in; (void)out_size; (void)ws_size;
  const float* hidden = (const float*)d_in[0];
  const float* wqkv   = (const float*)d_in[1];
  const float* bqkv   = (const float*)d_in[2];
  const float* relw   = (const float*)d_in[3];
  const float* relb   = (const float*)d_in[4];
  const float* outw   = (const float*)d_in[5];
  const float* outb   = (const float*)d_in[6];
  const int* ibm = (const int*)d_in[9];
  const int* ibn = (const int*)d_in[10];

  // workspace (~85 MB):
  //  Hb bf16 6291456 (hidden cast; reused as ATTb after mgemm<0>)
  //  Wc bf16 3670016 ; Ob bf16 1048576
  //  Qb/Kb/Vn bf16 [64 bh][1536 tok][64] ; VTb bf16 [64 bh][64 d][1536 tok]
  //  VALS fp32 [64 bh][1536 tok][32]
  unsigned short* Hb  = (unsigned short*)d_ws;
  unsigned short* Wc  = Hb + (size_t)6291456;
  unsigned short* Ob  = Wc + (size_t)3670016;
  unsigned short* Qb  = Ob + (size_t)1048576;
  unsigned short* Kb  = Qb + (size_t)6291456;
  unsigned short* Vn  = Kb + (size_t)6291456;
  unsigned short* VTb = Vn + (size_t)6291456;
  float* VLS = (float*)(VTb + (size_t)6291456);
  unsigned short* ATTb = Hb;   // alias: hidden-bf16 dead after mgemm<0>

  cast_k<<<5376, 256, 0, stream>>>(hidden, wqkv, relw, outw, Hb, Wc, Ob);
  mgemm<0><<<dim3(28, 48), 256, 0, stream>>>(Hb, Wc, bqkv, relb,
                                             Qb, Kb, Vn, VLS, nullptr);
  vtr<<<dim3(24, 64), 256, 0, stream>>>(Vn, VTb);
  fattn<<<1536, 256, 0, stream>>>(Qb, Kb, VTb, VLS, ibm, ibn, ATTb);
  mgemm<1><<<dim3(8, 96), 256, 0, stream>>>(ATTb, Ob, outb, nullptr,
                                            nullptr, nullptr, nullptr, nullptr,
                                            (float*)d_out);
}

// Round 7
// 297.343 us; speedup vs baseline: 1.1434x; 1.1434x over previous
//
#include <hip/hip_runtime.h>
#include <stdint.h>

#define T_LEN 512
#define NTOK  1536   // (1+NGRAM)*T
#define EMB   1024
#define BS    4

typedef __bf16 bf16x8 __attribute__((ext_vector_type(8)));
typedef float  f32x4  __attribute__((ext_vector_type(4)));

__device__ __forceinline__ float bflo(unsigned short u){
  union { unsigned int i; float f; } a; a.i = ((unsigned int)u) << 16; return a.f;
}
__device__ __forceinline__ unsigned short f2bf(float f){
  union { float f; unsigned int i; } v; v.f = f;
  unsigned int x = v.i;
  return (unsigned short)((x + 0x7fffu + ((x >> 16) & 1u)) >> 16); // RNE
}

__device__ __forceinline__ void gld_lds16(const unsigned short* gptr, unsigned short* lptr){
  __builtin_amdgcn_global_load_lds(
      (const __attribute__((address_space(1))) unsigned int*)gptr,
      (__attribute__((address_space(3))) unsigned int*)lptr, 16, 0, 0);
}

// ---------------------------------------------------------------------------
// fp32 -> bf16 cast pre-pass (hidden, wqkv++relw, outw). 8 elems/thread.
// ---------------------------------------------------------------------------
__global__ __launch_bounds__(256)
void cast_k(const float* __restrict__ h, const float* __restrict__ wq,
            const float* __restrict__ rw, const float* __restrict__ ow,
            unsigned short* __restrict__ Hb, unsigned short* __restrict__ Wc,
            unsigned short* __restrict__ Ob)
{
  const size_t e = ((size_t)blockIdx.x * 256 + threadIdx.x) * 8;
  const float* src; unsigned short* dst;
  if (e < 6291456)            { src = h  + e;                 dst = Hb + e; }
  else if (e < 9437184)       { size_t o = e - 6291456;       src = wq + o; dst = Wc + o; }
  else if (e < 9961472)       { size_t o = e - 9437184;       src = rw + o; dst = Wc + 3145728 + o; }
  else                        { size_t o = e - 9961472;       src = ow + o; dst = Ob + o; }
  float4 f0 = *(const float4*)src, f1 = *(const float4*)(src + 4);
  unsigned short r[8];
  r[0]=f2bf(f0.x); r[1]=f2bf(f0.y); r[2]=f2bf(f0.z); r[3]=f2bf(f0.w);
  r[4]=f2bf(f1.x); r[5]=f2bf(f1.y); r[6]=f2bf(f1.z); r[7]=f2bf(f1.w);
  *(uint4*)dst = *(const uint4*)r;
}

// ---------------------------------------------------------------------------
// bf16 MFMA GEMM computing C^T (A-frags = weight rows, B-frags = token rows):
// lane's 4 C/D regs span 4 consecutive out-cols -> vectorized epilogue.
// MODE 0: 128-token tiles; W=Wc(3584 rows: 3072 qkv + 512 rel). Epilogue:
//   Q(x0.125)/K -> bf16 [bh][tok][64]; V -> bf16 natural [bh][tok][64]
//   (vtr transposes); rel-vals -> fp32 [bh][tok][32].
// MODE 1: 64-token tiles (768 blocks), W=Ob(outw), +outb -> fp32 d_out.
// ---------------------------------------------------------------------------
template<int MODE>
__global__ __launch_bounds__(256)
void mgemm(const unsigned short* __restrict__ A,
           const unsigned short* __restrict__ W,
           const float* __restrict__ B0,
           const float* __restrict__ B1,
           unsigned short* __restrict__ Qo, unsigned short* __restrict__ Ko,
           unsigned short* __restrict__ Vo, float* __restrict__ VALS,
           float* __restrict__ OUT)
{
  constexpr int TM = (MODE == 0) ? 128 : 64;
  constexpr int NI = (MODE == 0) ? 4 : 2;
  __shared__ unsigned short As[TM*32];
  __shared__ unsigned short Bs[128*32];
  const int K = 1024;
  const int m0 = blockIdx.y * TM, n0 = blockIdx.x * 128;
  const int tid = threadIdx.x;
  const int wid = tid >> 6, lane = tid & 63;
  const int l15 = lane & 15, q8 = (lane >> 4) * 8;
  const int srow = lane >> 2, schunk = (lane & 3) * 8;
  const int wcol = (MODE == 0) ? (wid >> 1) * 64 : wid * 32;
  const int wtok = (MODE == 0) ? (wid & 1) * 64 : 0;

  f32x4 acc[NI][4];
  #pragma unroll
  for (int i=0;i<NI;i++)
    #pragma unroll
    for (int j=0;j<4;j++)
      #pragma unroll
      for (int r=0;r<4;r++) acc[i][j][r] = 0.f;

  for (int k0 = 0; k0 < K; k0 += 32) {
    if (MODE == 0) {
      #pragma unroll
      for (int p = 0; p < 2; ++p) {
        const int r0 = p*64 + wid*16;
        gld_lds16(A + (size_t)(m0 + r0 + srow)*K + k0 + schunk, &As[r0*32]);
      }
    } else {
      const int r0 = wid*16;
      gld_lds16(A + (size_t)(m0 + r0 + srow)*K + k0 + schunk, &As[r0*32]);
    }
    #pragma unroll
    for (int p = 0; p < 2; ++p) {
      const int r0 = p*64 + wid*16;
      gld_lds16(W + (size_t)(n0 + r0 + srow)*K + k0 + schunk, &Bs[r0*32]);
    }
    __syncthreads();
    bf16x8 wf[NI], hf[4];
    #pragma unroll
    for (int i=0;i<NI;i++) wf[i] = *(const bf16x8*)&Bs[(wcol + i*16 + l15)*32 + q8];
    #pragma unroll
    for (int j=0;j<4;j++)  hf[j] = *(const bf16x8*)&As[(wtok + j*16 + l15)*32 + q8];
    #pragma unroll
    for (int i=0;i<NI;i++)
      #pragma unroll
      for (int j=0;j<4;j++)
        acc[i][j] = __builtin_amdgcn_mfma_f32_16x16x32_bf16(wf[i], hf[j], acc[i][j], 0, 0, 0);
    __syncthreads();
  }

  const int rbase = (lane >> 4) * 4;
  #pragma unroll
  for (int i=0;i<NI;i++){
    const int c0 = n0 + wcol + i*16 + rbase;
    float4 b4;
    if (MODE==0) b4 = (c0 < 3072) ? *(const float4*)&B0[c0]
                                  : *(const float4*)&B1[c0-3072];
    else         b4 = *(const float4*)&B0[c0];
    #pragma unroll
    for (int j=0;j<4;j++){
      const int tokrow = m0 + wtok + j*16 + l15; // = tok*B + b
      float v[4];
      v[0]=acc[i][j][0]+b4.x; v[1]=acc[i][j][1]+b4.y;
      v[2]=acc[i][j][2]+b4.z; v[3]=acc[i][j][3]+b4.w;
      if (MODE==1){
        float4 st; st.x=v[0]; st.y=v[1]; st.z=v[2]; st.w=v[3];
        *(float4*)&OUT[(size_t)tokrow*EMB + c0] = st;
      } else {
        const int tok = tokrow >> 2, bb = tokrow & 3;
        if (c0 < 3072){
          const int which = c0 >> 10, e = c0 & 1023;
          const int h = e >> 6, d0 = e & 63;
          const float sc = (which==0) ? 0.125f : 1.0f;
          unsigned short pk[4];
          #pragma unroll
          for (int r=0;r<4;r++) pk[r] = f2bf(v[r]*sc);
          unsigned short* base = (which==0) ? Qo : (which==1) ? Ko : Vo;
          *(uint2*)&base[((size_t)(bb*16+h)*NTOK + tok)*64 + d0] = *(const uint2*)pk;
        } else {
          const int nb = (c0 - 3072) >> 4;
          #pragma unroll
          for (int r=0;r<4;r++)
            VALS[((size_t)(bb*16 + rbase + r)*NTOK + tok)*32 + nb] = v[r];
        }
      }
    }
  }
}

// ---------------------------------------------------------------------------
// V transpose: Vn [bh][tok][64] -> VT [bh][d][tok]. 64x64 tiles via LDS.
// ---------------------------------------------------------------------------
__global__ __launch_bounds__(256)
void vtr(const unsigned short* __restrict__ Vn, unsigned short* __restrict__ VT)
{
  __shared__ unsigned short t[64*72];
  const int bh = blockIdx.y, t0 = blockIdx.x * 64;
  const int tid = threadIdx.x;
  const int row = tid & 63, seg = tid >> 6;
  const unsigned short* src = Vn + ((size_t)bh*NTOK + t0 + row)*64 + seg*16;
  *(uint4*)&t[row*72 + seg*16]     = *(const uint4*)src;
  *(uint4*)&t[row*72 + seg*16 + 8] = *(const uint4*)(src + 8);
  __syncthreads();
  unsigned short v[16];
  #pragma unroll
  for (int k=0;k<16;k++) v[k] = t[(seg*16+k)*72 + row];
  unsigned short* dst = VT + ((size_t)bh*64 + row)*NTOK + t0 + seg*16;
  *(uint4*)dst       = *(const uint4*)&v[0];
  *(uint4*)(dst + 8) = *(const uint4*)&v[8];
}

// ---------------------------------------------------------------------------
// MFMA flash attention, work-shared: block = (bh, pr) handles ALL 6 contexts
// (3 streams x q-tiles {pr, 7-pr}) that attend the same main-key tiles.
// Grid 256, every block exactly 9 tile-units (perfect balance). Per tile:
// K/V frags loaded ONCE, reused by 6 independent S/exp/PV chains (6x less
// fetch than R6, 6x the ILP per load). Per-context math identical to the
// verified R4 kernel. 4 waves x 16 q-rows; no barriers in the tile loop
// (Pl is per-wave). VGPR ~260 -> launch_bounds(256,1): 1 block/CU by design.
// ---------------------------------------------------------------------------
__global__ __launch_bounds__(256, 1)
void fattn(const unsigned short* __restrict__ Q,
           const unsigned short* __restrict__ K,
           const unsigned short* __restrict__ VT,
           const float* __restrict__ VALS,
           const int* __restrict__ IBM,
           const int* __restrict__ IBN,
           unsigned short* __restrict__ OUT)
{
  __shared__ float vls[6][64*33];          // 50688 B
  __shared__ unsigned short Pl[4][16*72];  //  9216 B
  __shared__ int fs[513];
  __shared__ float pex[4][16];
  __shared__ float lar[4][16];

  const int pr = blockIdx.x & 3, bh = blockIdx.x >> 2;
  const int qlo = pr, qhi = 7 - pr;
  const int tid = threadIdx.x, wid = tid >> 6, lane = tid & 63;
  const int l15 = lane & 15, q4 = lane >> 4;

  fs[tid]       = IBM[(size_t)tid * T_LEN];
  fs[tid + 256] = IBM[(size_t)(tid + 256) * T_LEN];
  if (tid == 0) fs[512] = IBN[(size_t)511 * (2*T_LEN)];

  int tokbase[6];
  #pragma unroll
  for (int c=0;c<6;c++){
    const int s = c >> 1;
    const int qt = (c & 1) ? qhi : qlo;
    tokbase[c] = s*T_LEN + qt*64;
  }
  { // stage the 6 VALS tiles (fp32, row pad 33)
    const int row = tid >> 2, c8 = (tid & 3) * 8;
    #pragma unroll
    for (int c=0;c<6;c++){
      const float* vsrc = VALS + ((size_t)bh*NTOK + tokbase[c] + row)*32 + c8;
      *(float4*)&vls[c][row*33 + c8]     = *(const float4*)vsrc;
      *(float4*)&vls[c][row*33 + c8 + 4] = *(const float4*)(vsrc + 4);
    }
  }

  const unsigned short* Kbh = K  + (size_t)bh*NTOK*64;
  const unsigned short* Vbh = VT + (size_t)bh*64*NTOK;

  bf16x8 bq[6][2];
  #pragma unroll
  for (int c=0;c<6;c++){
    const unsigned short* qp = Q + ((size_t)bh*NTOK + tokbase[c] + wid*16 + l15)*64 + q4*8;
    bq[c][0] = *(const bf16x8*)qp;
    bq[c][1] = *(const bf16x8*)(qp + 32);
  }

  f32x4 o[6][4];
  float lr[6];
  #pragma unroll
  for (int c=0;c<6;c++){
    lr[c] = 0.f;
    #pragma unroll
    for (int jd=0;jd<4;jd++)
      #pragma unroll
      for (int r=0;r<4;r++) o[c][jd][r] = 0.f;
  }
  const f32x4 zero = {0.f,0.f,0.f,0.f};
  unsigned short* Pw = &Pl[wid][0];

  __syncthreads();   // vls/fs ready

  for (int tile = 0; tile <= qhi; ++tile) {
    const int u0 = tile * 64;
    // shared K/V fragments for this tile (used by all active contexts)
    bf16x8 ka0[4], ka1[4], vb0[4], vb1[4];
    #pragma unroll
    for (int i=0;i<4;i++){
      const unsigned short* kp = Kbh + (size_t)(u0 + 16*i + l15)*64 + q4*8;
      ka0[i] = *(const bf16x8*)kp;  ka1[i] = *(const bf16x8*)(kp + 32);
      const unsigned short* vp = Vbh + (size_t)(16*i + l15)*NTOK + u0 + q4*8;
      vb0[i] = *(const bf16x8*)vp;  vb1[i] = *(const bf16x8*)(vp + 32);
    }
    #pragma unroll
    for (int c=0;c<6;c++){
      const int qt = (c & 1) ? qhi : qlo;
      if (tile > qt) continue;                 // wave-uniform
      const int t = qt*64 + wid*16 + l15;
      const int relofs = (c >= 2) ? 1 : 0;     // streams s>0
      // S^T = K . Q^T
      f32x4 st[4];
      #pragma unroll
      for (int i=0;i<4;i++){
        st[i] = __builtin_amdgcn_mfma_f32_16x16x32_bf16(ka0[i], bq[c][0], zero, 0, 0, 0);
        st[i] = __builtin_amdgcn_mfma_f32_16x16x32_bf16(ka1[i], bq[c][1], st[i], 0, 0, 0);
      }
      // mask + rel + exp; pack P -> per-wave LDS; row sums
      float lp = 0.f;
      #pragma unroll
      for (int i=0;i<4;i++){
        unsigned short pr4[4];
        #pragma unroll
        for (int r=0;r<4;r++){
          const int u = u0 + 16*i + q4*4 + r;
          const bool ok = (u <= t);
          const int nd = ok ? (t - u + relofs) : 0;
          const float rel = vls[c][(wid*16 + l15)*33 + fs[nd]];
          float p = ok ? __expf(st[i][r] + rel) : 0.f;
          const unsigned short pb = f2bf(p);
          pr4[r] = pb;
          lp += bflo(pb);
        }
        uint2 pk;
        pk.x = (unsigned int)pr4[0] | ((unsigned int)pr4[1] << 16);
        pk.y = (unsigned int)pr4[2] | ((unsigned int)pr4[3] << 16);
        *(uint2*)&Pw[l15*72 + 16*i + q4*4] = pk;
      }
      lp += __shfl_xor(lp, 16);
      lp += __shfl_xor(lp, 32);
      lr[c] += lp;
      // O += P . V
      bf16x8 ap0 = *(const bf16x8*)&Pw[l15*72 + q4*8];
      bf16x8 ap1 = *(const bf16x8*)&Pw[l15*72 + 32 + q4*8];
      #pragma unroll
      for (int jd=0;jd<4;jd++){
        o[c][jd] = __builtin_amdgcn_mfma_f32_16x16x32_bf16(ap0, vb0[jd], o[c][jd], 0, 0, 0);
        o[c][jd] = __builtin_amdgcn_mfma_f32_16x16x32_bf16(ap1, vb1[jd], o[c][jd], 0, 0, 0);
      }
    }
  }

  // ngram tails: contexts c>=2 add exactly one key at token qtok (bucket fs[0])
  #pragma unroll
  for (int c=2;c<6;c++){
    const int qtok = tokbase[c] + wid*16 + l15;
    const unsigned short* qp2 = Q + ((size_t)bh*NTOK + qtok)*64 + q4*16;
    const unsigned short* kp2 = Kbh + (size_t)qtok*64 + q4*16;
    float s = 0.f;
    #pragma unroll
    for (int cc=0;cc<2;cc++){
      bf16x8 qv = *(const bf16x8*)(qp2 + cc*8);
      bf16x8 kv = *(const bf16x8*)(kp2 + cc*8);
      #pragma unroll
      for (int e=0;e<8;e++) s += (float)qv[e] * (float)kv[e];
    }
    s += __shfl_xor(s, 16);
    s += __shfl_xor(s, 32);
    const float p = __expf(s + vls[c][(wid*16 + l15)*33 + fs[0]]);
    lr[c] += p;
    pex[wid][l15] = p;                 // intra-wave exchange
    #pragma unroll
    for (int r=0;r<4;r++){
      const int qloc = q4*4 + r;
      const float pq = pex[wid][qloc];
      const int qtk = tokbase[c] + wid*16 + qloc;
      #pragma unroll
      for (int jd=0;jd<4;jd++){
        const float vv = bflo(Vbh[(size_t)(16*jd + l15)*NTOK + qtk]);
        o[c][jd][r] += pq * vv;
      }
    }
  }

  // epilogue per context
  const int b = bh >> 4, h = bh & 15;
  #pragma unroll
  for (int c=0;c<6;c++){
    lar[wid][l15] = lr[c];             // intra-wave exchange (serial reuse)
    #pragma unroll
    for (int r=0;r<4;r++){
      const int qloc = q4*4 + r;
      const float inv = 1.0f / lar[wid][qloc];
      const int qtk = tokbase[c] + wid*16 + qloc;
      unsigned short* orow = OUT + ((size_t)qtk*BS + b)*EMB + h*64 + l15;
      #pragma unroll
      for (int jd=0;jd<4;jd++)
        orow[16*jd] = f2bf(o[c][jd][r] * inv);
    }
  }
}

// ---------------------------------------------------------------------------
extern "C" void kernel_launch(void* const* d_in, const int* in_sizes, int n_in,
                              void* d_out, int out_size, void* d_ws, size_t ws_size,
                              hipStream_t stream) {
  (void)in_sizes; (void)n_in; (void)out_size; (void)ws_size;
  const float* hidden = (const float*)d_in[0];
  const float* wqkv   = (const float*)d_in[1];
  const float* bqkv   = (const float*)d_in[2];
  const float* relw   = (const float*)d_in[3];
  const float* relb   = (const float*)d_in[4];
  const float* outw   = (const float*)d_in[5];
  const float* outb   = (const float*)d_in[6];
  const int* ibm = (const int*)d_in[9];
  const int* ibn = (const int*)d_in[10];

  unsigned short* Hb  = (unsigned short*)d_ws;
  unsigned short* Wc  = Hb + (size_t)6291456;
  unsigned short* Ob  = Wc + (size_t)3670016;
  unsigned short* Qb  = Ob + (size_t)1048576;
  unsigned short* Kb  = Qb + (size_t)6291456;
  unsigned short* Vn  = Kb + (size_t)6291456;
  unsigned short* VTb = Vn + (size_t)6291456;
  float* VLS = (float*)(VTb + (size_t)6291456);
  unsigned short* ATTb = Hb;   // alias: hidden-bf16 dead after mgemm<0>

  cast_k<<<5376, 256, 0, stream>>>(hidden, wqkv, relw, outw, Hb, Wc, Ob);
  mgemm<0><<<dim3(28, 48), 256, 0, stream>>>(Hb, Wc, bqkv, relb,
                                             Qb, Kb, Vn, VLS, nullptr);
  vtr<<<dim3(24, 64), 256, 0, stream>>>(Vn, VTb);
  fattn<<<256, 256, 0, stream>>>(Qb, Kb, VTb, VLS, ibm, ibn, ATTb);
  mgemm<1><<<dim3(8, 96), 256, 0, stream>>>(ATTb, Ob, outb, nullptr,
                                            nullptr, nullptr, nullptr, nullptr,
                                            (float*)d_out);
}